// Round 2
// baseline (198.847 us; speedup 1.0000x reference)
//
#include <hip/hip_runtime.h>
#include <math.h>

#define B 4
#define DEC 256
#define ENC 256
#define HDIM 512

// 2*log2(e): projections pre-scaled so exp2(dp'+ep') == e^{2*(dp+ep+b_mlp)}
#define TANH_SCALE 2.8853900817779268f
#define LOG2E 1.4426950408889634f

__device__ __forceinline__ float fast_exp2(float x) { return __builtin_amdgcn_exp2f(x); }
__device__ __forceinline__ float fast_rcp(float x)  { return __builtin_amdgcn_rcpf(x); }

// ---------------------------------------------------------------------------
// 32(r) x 64(m) fp32 GEMM tile, K-chunks of 32, register-prefetch of the next
// chunk ahead of the LDS barrier. block = 256 threads, 2x4 outputs/thread.
// W row stride fixed 512 (true for W_mlp and for encoder_states).
// transposed=false: out[r][m] (row stride 512)
// transposed=true : outT[m][e] (row stride 256), e = r % 256 (batch handled by caller)
// ---------------------------------------------------------------------------
__device__ __forceinline__ void gemm32x64(
    const float* __restrict__ X, int xstride, int K,
    const float* __restrict__ W,
    const float* __restrict__ bias, float scale,
    float* __restrict__ out, bool transposed,
    int r0, int m0, float (*As)[33], float (*Bs)[68])
{
    const int tid = threadIdx.x;
    const int ra = tid >> 3, ka4 = (tid & 7) << 2;   // A: 32r x 32k, 1 float4/thread
    const int kb = tid >> 4, mb4 = (tid & 15) << 2;  // B: 32k x 64m, 2 float4/thread
    const int tx = tid & 15, ty = tid >> 4;          // out: ty -> 2 rows, tx -> 4 cols

    float acc[2][4] = {};

    float4 a4 = *(const float4*)(X + (long)(r0 + ra) * xstride + ka4);
    float4 b4 = *(const float4*)(W + (long)kb * 512 + m0 + mb4);
    float4 b4b = *(const float4*)(W + (long)(kb + 16) * 512 + m0 + mb4);

    for (int k0 = 0; k0 < K; k0 += 32) {
        As[ka4 + 0][ra] = a4.x; As[ka4 + 1][ra] = a4.y;
        As[ka4 + 2][ra] = a4.z; As[ka4 + 3][ra] = a4.w;
        *(float4*)&Bs[kb][mb4] = b4;
        *(float4*)&Bs[kb + 16][mb4] = b4b;
        __syncthreads();
        if (k0 + 32 < K) {   // prefetch next chunk while consuming this one
            a4 = *(const float4*)(X + (long)(r0 + ra) * xstride + k0 + 32 + ka4);
            b4 = *(const float4*)(W + (long)(k0 + 32 + kb) * 512 + m0 + mb4);
            b4b = *(const float4*)(W + (long)(k0 + 48 + kb) * 512 + m0 + mb4);
        }
#pragma unroll
        for (int k = 0; k < 32; ++k) {
            float2 av = *(const float2*)&As[k][ty << 1];
            float4 bv = *(const float4*)&Bs[k][tx << 2];
            acc[0][0] = fmaf(av.x, bv.x, acc[0][0]);
            acc[0][1] = fmaf(av.x, bv.y, acc[0][1]);
            acc[0][2] = fmaf(av.x, bv.z, acc[0][2]);
            acc[0][3] = fmaf(av.x, bv.w, acc[0][3]);
            acc[1][0] = fmaf(av.y, bv.x, acc[1][0]);
            acc[1][1] = fmaf(av.y, bv.y, acc[1][1]);
            acc[1][2] = fmaf(av.y, bv.z, acc[1][2]);
            acc[1][3] = fmaf(av.y, bv.w, acc[1][3]);
        }
        __syncthreads();
    }

    float4 bv = make_float4(0.f, 0.f, 0.f, 0.f);
    if (bias) bv = *(const float4*)(bias + m0 + (tx << 2));
    float o[2][4];
#pragma unroll
    for (int i = 0; i < 2; ++i) {
        o[i][0] = (acc[i][0] + bv.x) * scale;
        o[i][1] = (acc[i][1] + bv.y) * scale;
        o[i][2] = (acc[i][2] + bv.z) * scale;
        o[i][3] = (acc[i][3] + bv.w) * scale;
    }
    if (!transposed) {
#pragma unroll
        for (int i = 0; i < 2; ++i)
            *(float4*)(out + (long)(r0 + (ty << 1) + i) * 512 + m0 + (tx << 2)) =
                make_float4(o[i][0], o[i][1], o[i][2], o[i][3]);
    } else {
        const int e = (r0 & 255) + (ty << 1);
#pragma unroll
        for (int j = 0; j < 4; ++j)   // outT[m][e], float2 along e
            *(float2*)(out + (long)(m0 + (tx << 2) + j) * 256 + e) =
                make_float2(o[0][j], o[1][j]);
    }
}

// z=0: enc @ W_mlp[:H] -> epT[b][m][e] (transposed, scaled)
// z=1: dec @ W_mlp[H:] + b_mlp -> dpb[b*DEC+d][m] (row-major, scaled)
__global__ __launch_bounds__(256) void proj_kernel(
    const float* __restrict__ enc, const float* __restrict__ dec,
    const float* __restrict__ Wmlp, const float* __restrict__ bmlp,
    float* __restrict__ epT, float* __restrict__ dpb)
{
    __shared__ __align__(16) float As[32][33];
    __shared__ __align__(16) float Bs[32][68];
    const int r0 = blockIdx.y * 32, m0 = blockIdx.x * 64;
    if (blockIdx.z == 0) {
        float* outT = epT + (long)(r0 >> 8) * HDIM * ENC;  // batch = r0/256
        gemm32x64(enc, HDIM, HDIM, Wmlp, nullptr, TANH_SCALE,
                  outT, true, r0, m0, As, Bs);
    } else {
        gemm32x64(dec, HDIM, HDIM, Wmlp + HDIM * HDIM, bmlp, TANH_SCALE,
                  dpb, false, r0, m0, As, Bs);
    }
}

// context[b,d,:] = attn[b,d,:] @ enc[b,:,:]
__global__ __launch_bounds__(256) void context_kernel(
    const float* __restrict__ attn, const float* __restrict__ enc,
    float* __restrict__ ctx)
{
    __shared__ __align__(16) float As[32][33];
    __shared__ __align__(16) float Bs[32][68];
    const int b = blockIdx.z;
    gemm32x64(attn + (long)b * DEC * ENC, ENC, ENC,
              enc + (long)b * ENC * HDIM, nullptr, 1.0f,
              ctx + (long)b * DEC * HDIM, false,
              blockIdx.y * 32, blockIdx.x * 64, As, Bs);
}

// ---------------------------------------------------------------------------
// Fused logits + masks + softmax. thread = e (256/block), 2 decoder rows per
// block. No inner-loop LDS/barriers: ep read coalesced from epT[b][m][e],
// dp/wo are wave-uniform (scalar) loads. Register double-buffer on ep.
// logit = (SumWo + b_out) - 2 * sum_m wo[m] * rcp(1 + exp2(dp'[d,m]+ep'[e,m]))
// ---------------------------------------------------------------------------
__global__ __launch_bounds__(256) void attn_kernel(
    const float* __restrict__ dpb, const float* __restrict__ epT,
    const float* __restrict__ wo, const float* __restrict__ bout,
    const float* __restrict__ enc, const unsigned char* __restrict__ extm,
    float* __restrict__ attn_out)
{
    __shared__ float sred[4];
    __shared__ float red[2][4][2];

    const int tid = threadIdx.x, lane = tid & 63, wave = tid >> 6;
    const int b = blockIdx.y, d0 = blockIdx.x * 2;

    // block-wide sum of wo (512 entries)
    float w2 = wo[tid] + wo[tid + 256];
#pragma unroll
    for (int off = 32; off >= 1; off >>= 1) w2 += __shfl_xor(w2, off, 64);
    if (lane == 0) sred[wave] = w2;
    __syncthreads();
    const float base = sred[0] + sred[1] + sred[2] + sred[3] + bout[0];

    const float* dpr0 = dpb + ((long)b * DEC + d0) * HDIM;
    const float* dpr1 = dpr0 + HDIM;
    const float* ept = epT + (long)b * HDIM * ENC + tid;

    float acc0 = 0.f, acc1 = 0.f;
    float ev[8], nv[8];
#pragma unroll
    for (int j = 0; j < 8; ++j) ev[j] = ept[j * 256];

    for (int m = 0; m < HDIM; m += 8) {
        if (m + 8 < HDIM) {
#pragma unroll
            for (int j = 0; j < 8; ++j) nv[j] = ept[(m + 8 + j) * 256];
        }
#pragma unroll
        for (int j = 0; j < 8; ++j) {
            float w = wo[m + j];          // uniform -> s_load
            float x0 = ev[j] + dpr0[m + j];
            float x1 = ev[j] + dpr1[m + j];
            acc0 = fmaf(w, fast_rcp(fast_exp2(x0) + 1.0f), acc0);
            acc1 = fmaf(w, fast_rcp(fast_exp2(x1) + 1.0f), acc1);
        }
#pragma unroll
        for (int j = 0; j < 8; ++j) ev[j] = nv[j];
    }

    // masks
    const int e = tid;
    const bool pad = (enc[((long)b * ENC + e) * HDIM] == 0.0f);
    const bool x0m = extm[((long)(b * DEC) + d0) * ENC + e] != 0;
    const bool x1m = extm[((long)(b * DEC) + d0 + 1) * ENC + e] != 0;
    float l0 = (pad || x0m) ? -__builtin_inff() : base - 2.0f * acc0;
    float l1 = (pad || x1m) ? -__builtin_inff() : base - 2.0f * acc1;

    // softmax over e (4 waves)
    float m0 = l0, m1 = l1;
#pragma unroll
    for (int off = 32; off >= 1; off >>= 1) {
        m0 = fmaxf(m0, __shfl_xor(m0, off, 64));
        m1 = fmaxf(m1, __shfl_xor(m1, off, 64));
    }
    if (lane == 0) { red[0][wave][0] = m0; red[0][wave][1] = m1; }
    __syncthreads();
    const float gm0 = fmaxf(fmaxf(red[0][0][0], red[0][1][0]), fmaxf(red[0][2][0], red[0][3][0]));
    const float gm1 = fmaxf(fmaxf(red[0][0][1], red[0][1][1]), fmaxf(red[0][2][1], red[0][3][1]));
    float p0 = fast_exp2((l0 - gm0) * LOG2E);
    float p1 = fast_exp2((l1 - gm1) * LOG2E);
    float s0 = p0, s1 = p1;
#pragma unroll
    for (int off = 32; off >= 1; off >>= 1) {
        s0 += __shfl_xor(s0, off, 64);
        s1 += __shfl_xor(s1, off, 64);
    }
    if (lane == 0) { red[1][wave][0] = s0; red[1][wave][1] = s1; }
    __syncthreads();
    const float gs0 = red[1][0][0] + red[1][1][0] + red[1][2][0] + red[1][3][0];
    const float gs1 = red[1][0][1] + red[1][1][1] + red[1][2][1] + red[1][3][1];
    attn_out[((long)(b * DEC) + d0) * ENC + e] = p0 * fast_rcp(gs0);
    attn_out[((long)(b * DEC) + d0 + 1) * ENC + e] = p1 * fast_rcp(gs1);
}

// ---------------------------------------------------------------------------
extern "C" void kernel_launch(void* const* d_in, const int* in_sizes, int n_in,
                              void* d_out, int out_size, void* d_ws, size_t ws_size,
                              hipStream_t stream) {
    const float* dec = (const float*)d_in[0];
    const float* enc = (const float*)d_in[1];
    const unsigned char* extm = (const unsigned char*)d_in[2];
    const float* Wmlp = (const float*)d_in[3];
    const float* bmlp = (const float*)d_in[4];
    const float* Wout = (const float*)d_in[5];
    const float* bout = (const float*)d_in[6];

    float* ctx = (float*)d_out;                    // [B, DEC, H]
    float* attn = ctx + (size_t)B * DEC * HDIM;    // [B, DEC, ENC]

    float* epT = (float*)d_ws;                     // [B][H][ENC] scaled enc-proj, transposed
    float* dpb = epT + (size_t)B * HDIM * ENC;     // [B*DEC][H] scaled dec-proj + bias

    // 1) projections: z=0 enc (transposed out), z=1 dec. 512 blocks.
    proj_kernel<<<dim3(8, 32, 2), 256, 0, stream>>>(enc, dec, Wmlp, bmlp, epT, dpb);
    // 2) fused tanh-MLP logits + masks + softmax. 512 blocks.
    attn_kernel<<<dim3(DEC / 2, B), 256, 0, stream>>>(dpb, epT, Wout, bout, enc, extm, attn);
    // 3) context = attn @ enc. 256 blocks.
    context_kernel<<<dim3(8, 8, 4), 256, 0, stream>>>(attn, enc, ctx);
}

// Round 3
// 148.233 us; speedup vs baseline: 1.3415x; 1.3415x over previous
//
#include <hip/hip_runtime.h>
#include <math.h>

#define B 4
#define DEC 256
#define ENC 256
#define HDIM 512

// 2*log2(e): exp2(x*TANH_SCALE) == e^{2x};  tanh(x) = 1 - 2/(1+e^{2x})
#define TANH_SCALE 2.8853900817779268f
#define LOG2E 1.4426950408889634f

__device__ __forceinline__ float fast_exp2(float x) { return __builtin_amdgcn_exp2f(x); }
__device__ __forceinline__ float fast_rcp(float x)  { return __builtin_amdgcn_rcpf(x); }

// ---------------------------------------------------------------------------
// proj: broadcast-GEMM, no LDS, no barriers. Block = 256 thr = 2 waves-pairs:
// tx = tid&127 -> m-quad (128 quads = all 512 m), ty = tid>>7 -> row-half.
// Each block: 8 rows x 512 m; each thread: 4 rows x 4 m = 16 acc.
// X-row loads are wave-uniform (1-line broadcast); W loads coalesced float4.
// Ping-pong register double-buffer, K-chunks of 8, two chunks per iter.
//  z=0: E^T[b][m][e] = exp2(TANH_SCALE * enc@W_mlp[:H])   (transposed store)
//  z=1: D[b*DEC+d][m] = exp2(TANH_SCALE * (dec@W_mlp[H:] + b_mlp))
// ---------------------------------------------------------------------------
#define PROJ_FMA(XB, WB)                                                    \
    _Pragma("unroll")                                                       \
    for (int kk = 0; kk < 8; ++kk) {                                        \
        _Pragma("unroll")                                                   \
        for (int i = 0; i < 4; ++i) {                                       \
            float xv = ((const float*)&XB[i][kk >> 2])[kk & 3];             \
            acc[i][0] = fmaf(xv, WB[kk].x, acc[i][0]);                      \
            acc[i][1] = fmaf(xv, WB[kk].y, acc[i][1]);                      \
            acc[i][2] = fmaf(xv, WB[kk].z, acc[i][2]);                      \
            acc[i][3] = fmaf(xv, WB[kk].w, acc[i][3]);                      \
        }                                                                   \
    }

#define PROJ_LOAD(XB, WB, KOFF)                                             \
    _Pragma("unroll")                                                       \
    for (int kk = 0; kk < 8; ++kk)                                          \
        WB[kk] = *(const float4*)&W[(long)((KOFF) + kk) * 512 + m0];        \
    _Pragma("unroll")                                                       \
    for (int i = 0; i < 4; ++i) {                                           \
        XB[i][0] = *(const float4*)&xrow[(long)i * 512 + (KOFF)];           \
        XB[i][1] = *(const float4*)&xrow[(long)i * 512 + (KOFF) + 4];       \
    }

__global__ __launch_bounds__(256) void proj_kernel(
    const float* __restrict__ enc, const float* __restrict__ dec,
    const float* __restrict__ Wmlp, const float* __restrict__ bmlp,
    float* __restrict__ ET, float* __restrict__ Dmat)
{
    const int tid = threadIdx.x;
    const int tx = tid & 127, ty = tid >> 7;
    const int r0 = blockIdx.x * 8 + ty * 4;
    const int m0 = tx * 4;
    const bool encside = (blockIdx.z == 0);
    const float* X = encside ? enc : dec;
    const float* W = encside ? Wmlp : (Wmlp + HDIM * HDIM);
    const float* xrow = X + (long)r0 * HDIM;

    float acc[4][4] = {};
    float4 Wa[8], Wb[8], Xa[4][2], Xb[4][2];

    PROJ_LOAD(Xa, Wa, 0)
    for (int k0 = 0; k0 < HDIM; k0 += 16) {
        PROJ_LOAD(Xb, Wb, k0 + 8)
        PROJ_FMA(Xa, Wa)
        if (k0 + 16 < HDIM) { PROJ_LOAD(Xa, Wa, k0 + 16) }
        PROJ_FMA(Xb, Wb)
    }

    if (encside) {
        // E^T[b][m][e]: thread's 4 rows are 4 consecutive e -> float4 store
        float* outb = ET + (long)(r0 >> 8) * HDIM * ENC + (r0 & 255);
#pragma unroll
        for (int j = 0; j < 4; ++j) {
            float4 v;
            v.x = fast_exp2(acc[0][j] * TANH_SCALE);
            v.y = fast_exp2(acc[1][j] * TANH_SCALE);
            v.z = fast_exp2(acc[2][j] * TANH_SCALE);
            v.w = fast_exp2(acc[3][j] * TANH_SCALE);
            *(float4*)&outb[(long)(m0 + j) * ENC] = v;
        }
    } else {
        float* outb = Dmat + (long)r0 * HDIM + m0;
        const float4 bq = *(const float4*)&bmlp[m0];
#pragma unroll
        for (int i = 0; i < 4; ++i) {
            float4 v;
            v.x = fast_exp2((acc[i][0] + bq.x) * TANH_SCALE);
            v.y = fast_exp2((acc[i][1] + bq.y) * TANH_SCALE);
            v.z = fast_exp2((acc[i][2] + bq.z) * TANH_SCALE);
            v.w = fast_exp2((acc[i][3] + bq.w) * TANH_SCALE);
            *(float4*)&outb[(long)i * HDIM] = v;
        }
    }
}

// ---------------------------------------------------------------------------
// attn: thread = e (256/block), 2 decoder rows/block, 512 blocks.
// acc_d = sum_m wo[m] * rcp(1 + E[e,m]*D[d,m]); logit == -2*acc (softmax
// shift-invariance kills SumWo + b_out). E^T coalesced vector loads with
// register double-buffer; D/wo are block-uniform -> scalar loads.
// ---------------------------------------------------------------------------
__global__ __launch_bounds__(256) void attn_kernel(
    const float* __restrict__ Dmat, const float* __restrict__ ET,
    const float* __restrict__ wo,
    const float* __restrict__ enc, const unsigned char* __restrict__ extm,
    float* __restrict__ attn_out)
{
    __shared__ float red[2][4][2];
    const int tid = threadIdx.x, lane = tid & 63, wave = tid >> 6;
    const int b = blockIdx.y, d0 = blockIdx.x * 2;

    const float* D0 = Dmat + ((long)b * DEC + d0) * HDIM;
    const float* D1 = D0 + HDIM;
    const float* ecol = ET + (long)b * HDIM * ENC + tid;

    float acc0 = 0.f, acc1 = 0.f;
    float ev[8], nv[8];
#pragma unroll
    for (int j = 0; j < 8; ++j) ev[j] = ecol[j * ENC];

    for (int m = 0; m < HDIM; m += 8) {
        if (m + 8 < HDIM) {
#pragma unroll
            for (int j = 0; j < 8; ++j) nv[j] = ecol[(m + 8 + j) * ENC];
        }
#pragma unroll
        for (int j = 0; j < 8; ++j) {
            float w = wo[m + j];                    // uniform -> s_load
            float t0 = ev[j] * D0[m + j];
            float t1 = ev[j] * D1[m + j];
            acc0 = fmaf(w, fast_rcp(t0 + 1.0f), acc0);
            acc1 = fmaf(w, fast_rcp(t1 + 1.0f), acc1);
        }
#pragma unroll
        for (int j = 0; j < 8; ++j) ev[j] = nv[j];
    }

    // masks + effective logits (additive constants dropped)
    const int e = tid;
    const bool pad = (enc[((long)b * ENC + e) * HDIM] == 0.0f);
    const bool x0m = extm[((long)(b * DEC) + d0) * ENC + e] != 0;
    const bool x1m = extm[((long)(b * DEC) + d0 + 1) * ENC + e] != 0;
    float l0 = (pad || x0m) ? -__builtin_inff() : -2.0f * acc0;
    float l1 = (pad || x1m) ? -__builtin_inff() : -2.0f * acc1;

    // softmax over e (4 waves)
    float m0 = l0, m1 = l1;
#pragma unroll
    for (int off = 32; off >= 1; off >>= 1) {
        m0 = fmaxf(m0, __shfl_xor(m0, off, 64));
        m1 = fmaxf(m1, __shfl_xor(m1, off, 64));
    }
    if (lane == 0) { red[0][wave][0] = m0; red[0][wave][1] = m1; }
    __syncthreads();
    const float gm0 = fmaxf(fmaxf(red[0][0][0], red[0][1][0]), fmaxf(red[0][2][0], red[0][3][0]));
    const float gm1 = fmaxf(fmaxf(red[0][0][1], red[0][1][1]), fmaxf(red[0][2][1], red[0][3][1]));
    float p0 = fast_exp2((l0 - gm0) * LOG2E);
    float p1 = fast_exp2((l1 - gm1) * LOG2E);
    float s0 = p0, s1 = p1;
#pragma unroll
    for (int off = 32; off >= 1; off >>= 1) {
        s0 += __shfl_xor(s0, off, 64);
        s1 += __shfl_xor(s1, off, 64);
    }
    if (lane == 0) { red[1][wave][0] = s0; red[1][wave][1] = s1; }
    __syncthreads();
    const float gs0 = red[1][0][0] + red[1][1][0] + red[1][2][0] + red[1][3][0];
    const float gs1 = red[1][0][1] + red[1][1][1] + red[1][2][1] + red[1][3][1];
    attn_out[((long)(b * DEC) + d0) * ENC + e] = p0 * fast_rcp(gs0);
    attn_out[((long)(b * DEC) + d0 + 1) * ENC + e] = p1 * fast_rcp(gs1);
}

// ---------------------------------------------------------------------------
// context: ctx[b,d,:] = attn[b,d,:] @ enc[b]. Same broadcast-GEMM pattern.
// Block: 4 d-rows x 512 h; thread: 2 rows x 4 h. K = 256 (e). 256 blocks.
// ---------------------------------------------------------------------------
#define CTX_FMA(XB, WB)                                                     \
    _Pragma("unroll")                                                       \
    for (int kk = 0; kk < 8; ++kk) {                                        \
        _Pragma("unroll")                                                   \
        for (int i = 0; i < 2; ++i) {                                       \
            float xv = ((const float*)&XB[i][kk >> 2])[kk & 3];             \
            acc[i][0] = fmaf(xv, WB[kk].x, acc[i][0]);                      \
            acc[i][1] = fmaf(xv, WB[kk].y, acc[i][1]);                      \
            acc[i][2] = fmaf(xv, WB[kk].z, acc[i][2]);                      \
            acc[i][3] = fmaf(xv, WB[kk].w, acc[i][3]);                      \
        }                                                                   \
    }

#define CTX_LOAD(XB, WB, KOFF)                                              \
    _Pragma("unroll")                                                       \
    for (int kk = 0; kk < 8; ++kk)                                          \
        WB[kk] = *(const float4*)&W[(long)((KOFF) + kk) * 512 + m0];        \
    _Pragma("unroll")                                                       \
    for (int i = 0; i < 2; ++i) {                                           \
        XB[i][0] = *(const float4*)&arow[(long)i * ENC + (KOFF)];           \
        XB[i][1] = *(const float4*)&arow[(long)i * ENC + (KOFF) + 4];       \
    }

__global__ __launch_bounds__(256) void context_kernel(
    const float* __restrict__ attn, const float* __restrict__ enc,
    float* __restrict__ ctx)
{
    const int tid = threadIdx.x;
    const int tx = tid & 127, ty = tid >> 7;
    const int b = blockIdx.y;
    const int d0 = blockIdx.x * 4 + ty * 2;
    const int m0 = tx * 4;
    const float* arow = attn + ((long)b * DEC + d0) * ENC;
    const float* W = enc + (long)b * ENC * HDIM;

    float acc[2][4] = {};
    float4 Wa[8], Wb[8], Xa[2][2], Xb[2][2];

    CTX_LOAD(Xa, Wa, 0)
    for (int k0 = 0; k0 < ENC; k0 += 16) {
        CTX_LOAD(Xb, Wb, k0 + 8)
        CTX_FMA(Xa, Wa)
        if (k0 + 16 < ENC) { CTX_LOAD(Xa, Wa, k0 + 16) }
        CTX_FMA(Xb, Wb)
    }
#pragma unroll
    for (int i = 0; i < 2; ++i)
        *(float4*)&ctx[((long)b * DEC + d0 + i) * HDIM + m0] =
            make_float4(acc[i][0], acc[i][1], acc[i][2], acc[i][3]);
}

// ---------------------------------------------------------------------------
extern "C" void kernel_launch(void* const* d_in, const int* in_sizes, int n_in,
                              void* d_out, int out_size, void* d_ws, size_t ws_size,
                              hipStream_t stream) {
    const float* dec = (const float*)d_in[0];
    const float* enc = (const float*)d_in[1];
    const unsigned char* extm = (const unsigned char*)d_in[2];
    const float* Wmlp = (const float*)d_in[3];
    const float* bmlp = (const float*)d_in[4];
    const float* Wout = (const float*)d_in[5];
    // d_in[6] = b_out: additive constant, cancels in softmax

    float* ctx = (float*)d_out;                    // [B, DEC, H]
    float* attn = ctx + (size_t)B * DEC * HDIM;    // [B, DEC, ENC]

    float* ET = (float*)d_ws;                      // [B][H][ENC] exp2(scaled enc-proj), transposed
    float* Dmat = ET + (size_t)B * HDIM * ENC;     // [B*DEC][H] exp2(scaled dec-proj + bias)

    // 1) projections + exp2 epilogue. 256 blocks, no LDS, no barriers.
    proj_kernel<<<dim3(128, 1, 2), 256, 0, stream>>>(enc, dec, Wmlp, bmlp, ET, Dmat);
    // 2) fused rational-tanh logits + masks + softmax. 512 blocks.
    attn_kernel<<<dim3(DEC / 2, B), 256, 0, stream>>>(Dmat, ET, Wout, enc, extm, attn);
    // 3) context = attn @ enc. 256 blocks.
    context_kernel<<<dim3(DEC / 4, B), 256, 0, stream>>>(attn, enc, ctx);
}

// Round 4
// 136.181 us; speedup vs baseline: 1.4602x; 1.0885x over previous
//
#include <hip/hip_runtime.h>
#include <math.h>

#define B 4
#define DEC 256
#define ENC 256
#define HDIM 512

// exp2(x*TANH_SCALE) == e^{2x};  tanh(x) = 1 - 2/(1+e^{2x})
#define TANH_SCALE 2.8853900817779268f
#define LOG2E 1.4426950408889634f

__device__ __forceinline__ float fast_exp2(float x) { return __builtin_amdgcn_exp2f(x); }
__device__ __forceinline__ float fast_rcp(float x)  { return __builtin_amdgcn_rcpf(x); }

// ---------------------------------------------------------------------------
// proj: 4 rows x 512 m per block, 256 thr. tx = tid&127 -> m-quad (512 m),
// kh = tid>>7 -> K-half (256 k each; W rows fully partitioned -> no duplicate
// W loads within a block). Each thread: 4r x 4m x 256k, register ping-pong.
// LDS reduce of the two K-halves, then exp2 epilogue.
//  z=0: E^T[b][m][e] = exp2(TANH_SCALE * enc@W_mlp[:H])
//  z=1: D[b*DEC+d][m] = exp2(TANH_SCALE * (dec@W_mlp[H:] + b_mlp))
// grid (256, 1, 2) = 512 blocks -> 2 blocks/CU, 8 waves/CU.
// ---------------------------------------------------------------------------
#define PLOAD(XB, WB, KOFF)                                                 \
    _Pragma("unroll")                                                       \
    for (int kk = 0; kk < 8; ++kk)                                          \
        WB[kk] = *(const float4*)&Wp[(long)((KOFF) + kk) * 512 + m0];       \
    _Pragma("unroll")                                                       \
    for (int i = 0; i < 4; ++i) {                                           \
        XB[i][0] = *(const float4*)&xr[(long)i * HDIM + (KOFF)];            \
        XB[i][1] = *(const float4*)&xr[(long)i * HDIM + (KOFF) + 4];        \
    }

#define PFMA(XB, WB)                                                        \
    _Pragma("unroll")                                                       \
    for (int kk = 0; kk < 8; ++kk) {                                        \
        _Pragma("unroll")                                                   \
        for (int i = 0; i < 4; ++i) {                                       \
            float xv = ((const float*)&XB[i][kk >> 2])[kk & 3];             \
            acc[i][0] = fmaf(xv, WB[kk].x, acc[i][0]);                      \
            acc[i][1] = fmaf(xv, WB[kk].y, acc[i][1]);                      \
            acc[i][2] = fmaf(xv, WB[kk].z, acc[i][2]);                      \
            acc[i][3] = fmaf(xv, WB[kk].w, acc[i][3]);                      \
        }                                                                   \
    }

__global__ __launch_bounds__(256) void proj_kernel(
    const float* __restrict__ enc, const float* __restrict__ dec,
    const float* __restrict__ Wmlp, const float* __restrict__ bmlp,
    float* __restrict__ ET, float* __restrict__ Dmat)
{
    __shared__ float red[16][128];   // SoA: conflict-free
    const int tid = threadIdx.x;
    const int tx = tid & 127, kh = tid >> 7;
    const int m0 = tx * 4;
    const int r0 = blockIdx.x * 4;
    const bool encside = (blockIdx.z == 0);
    const float* X = encside ? enc : dec;
    const float* Wp = (encside ? Wmlp : Wmlp + HDIM * HDIM) + (long)kh * 256 * 512;
    const float* xr = X + (long)r0 * HDIM + kh * 256;

    float acc[4][4] = {};
    float4 Wa[8], Wb[8], Xa[4][2], Xb[4][2];

    PLOAD(Xa, Wa, 0)
    for (int k0 = 0; k0 < 256; k0 += 16) {
        PLOAD(Xb, Wb, k0 + 8)
        PFMA(Xa, Wa)
        if (k0 + 16 < 256) { PLOAD(Xa, Wa, k0 + 16) }
        PFMA(Xb, Wb)
    }

    if (kh == 1) {
#pragma unroll
        for (int i = 0; i < 4; ++i)
#pragma unroll
            for (int j = 0; j < 4; ++j)
                red[i * 4 + j][tx] = acc[i][j];
    }
    __syncthreads();
    if (kh == 0) {
#pragma unroll
        for (int i = 0; i < 4; ++i)
#pragma unroll
            for (int j = 0; j < 4; ++j)
                acc[i][j] += red[i * 4 + j][tx];

        if (encside) {
            // thread's 4 rows = 4 consecutive e -> float4 store along e
            float* outb = ET + (long)(r0 >> 8) * HDIM * ENC + (r0 & 255);
#pragma unroll
            for (int j = 0; j < 4; ++j) {
                float4 v;
                v.x = fast_exp2(acc[0][j] * TANH_SCALE);
                v.y = fast_exp2(acc[1][j] * TANH_SCALE);
                v.z = fast_exp2(acc[2][j] * TANH_SCALE);
                v.w = fast_exp2(acc[3][j] * TANH_SCALE);
                *(float4*)&outb[(long)(m0 + j) * ENC] = v;
            }
        } else {
            const float4 bq = *(const float4*)&bmlp[m0];
            float* outb = Dmat + (long)r0 * HDIM + m0;
#pragma unroll
            for (int i = 0; i < 4; ++i) {
                float4 v;
                v.x = fast_exp2((acc[i][0] + bq.x) * TANH_SCALE);
                v.y = fast_exp2((acc[i][1] + bq.y) * TANH_SCALE);
                v.z = fast_exp2((acc[i][2] + bq.z) * TANH_SCALE);
                v.w = fast_exp2((acc[i][3] + bq.w) * TANH_SCALE);
                *(float4*)&outb[(long)i * HDIM] = v;
            }
        }
    }
}

// ---------------------------------------------------------------------------
// attn: thread = e (256/block), 2 decoder rows/block, 512 blocks (2/CU).
// acc_d = sum_m wo[m] * rcp(fma(E[e,m], D[d,m], 1)); logit = -2*acc (constants
// cancel in softmax). 3 VALU insts/element. 16-deep register prefetch on E^T.
// ---------------------------------------------------------------------------
__global__ __launch_bounds__(256) void attn_kernel(
    const float* __restrict__ Dmat, const float* __restrict__ ET,
    const float* __restrict__ wo,
    const float* __restrict__ enc, const unsigned char* __restrict__ extm,
    float* __restrict__ attn_out)
{
    __shared__ float red[2][4][2];
    const int tid = threadIdx.x, lane = tid & 63, wave = tid >> 6;
    const int b = blockIdx.y, d0 = blockIdx.x * 2;

    const float* D0 = Dmat + ((long)b * DEC + d0) * HDIM;
    const float* D1 = D0 + HDIM;
    const float* ecol = ET + (long)b * HDIM * ENC + tid;

    float acc0 = 0.f, acc1 = 0.f;
    float ev[16], nv[16];
#pragma unroll
    for (int j = 0; j < 16; ++j) ev[j] = ecol[j * ENC];

    for (int m = 0; m < HDIM; m += 16) {
        if (m + 16 < HDIM) {
#pragma unroll
            for (int j = 0; j < 16; ++j) nv[j] = ecol[(m + 16 + j) * ENC];
        }
#pragma unroll
        for (int j = 0; j < 16; ++j) {
            float w = wo[m + j];                        // uniform -> s_load
            float t0 = fmaf(ev[j], D0[m + j], 1.0f);
            float t1 = fmaf(ev[j], D1[m + j], 1.0f);
            acc0 = fmaf(w, fast_rcp(t0), acc0);
            acc1 = fmaf(w, fast_rcp(t1), acc1);
        }
#pragma unroll
        for (int j = 0; j < 16; ++j) ev[j] = nv[j];
    }

    // masks + effective logits
    const int e = tid;
    const bool pad = (enc[((long)b * ENC + e) * HDIM] == 0.0f);
    const bool x0m = extm[((long)(b * DEC) + d0) * ENC + e] != 0;
    const bool x1m = extm[((long)(b * DEC) + d0 + 1) * ENC + e] != 0;
    float l0 = (pad || x0m) ? -__builtin_inff() : -2.0f * acc0;
    float l1 = (pad || x1m) ? -__builtin_inff() : -2.0f * acc1;

    // softmax over e (4 waves)
    float m0 = l0, m1 = l1;
#pragma unroll
    for (int off = 32; off >= 1; off >>= 1) {
        m0 = fmaxf(m0, __shfl_xor(m0, off, 64));
        m1 = fmaxf(m1, __shfl_xor(m1, off, 64));
    }
    if (lane == 0) { red[0][wave][0] = m0; red[0][wave][1] = m1; }
    __syncthreads();
    const float gm0 = fmaxf(fmaxf(red[0][0][0], red[0][1][0]), fmaxf(red[0][2][0], red[0][3][0]));
    const float gm1 = fmaxf(fmaxf(red[0][0][1], red[0][1][1]), fmaxf(red[0][2][1], red[0][3][1]));
    float p0 = fast_exp2((l0 - gm0) * LOG2E);
    float p1 = fast_exp2((l1 - gm1) * LOG2E);
    float s0 = p0, s1 = p1;
#pragma unroll
    for (int off = 32; off >= 1; off >>= 1) {
        s0 += __shfl_xor(s0, off, 64);
        s1 += __shfl_xor(s1, off, 64);
    }
    if (lane == 0) { red[1][wave][0] = s0; red[1][wave][1] = s1; }
    __syncthreads();
    const float gs0 = red[1][0][0] + red[1][1][0] + red[1][2][0] + red[1][3][0];
    const float gs1 = red[1][0][1] + red[1][1][1] + red[1][2][1] + red[1][3][1];
    attn_out[((long)(b * DEC) + d0) * ENC + e] = p0 * fast_rcp(gs0);
    attn_out[((long)(b * DEC) + d0 + 1) * ENC + e] = p1 * fast_rcp(gs1);
}

// ---------------------------------------------------------------------------
// context: 4 d x 256 h per block, 256 thr. tx = tid&63 -> h-quad, ty = tid>>6
// -> e-quarter (64 e each). Each thread: 4d x 4h x 64e; LDS 4-way reduce.
// grid (64, 2, B) = 512 blocks -> 2 blocks/CU.
// ---------------------------------------------------------------------------
#define CLOAD(XB, WB, KOFF)                                                 \
    _Pragma("unroll")                                                       \
    for (int kk = 0; kk < 8; ++kk)                                          \
        WB[kk] = *(const float4*)&We[(long)((KOFF) + kk) * HDIM];           \
    _Pragma("unroll")                                                       \
    for (int i = 0; i < 4; ++i) {                                           \
        XB[i][0] = *(const float4*)&ar[(long)i * ENC + (KOFF)];             \
        XB[i][1] = *(const float4*)&ar[(long)i * ENC + (KOFF) + 4];         \
    }

__global__ __launch_bounds__(256) void context_kernel(
    const float* __restrict__ attn, const float* __restrict__ enc,
    float* __restrict__ ctx)
{
    __shared__ float red[3][16][64];
    const int tid = threadIdx.x;
    const int tx = tid & 63, ty = tid >> 6;
    const int b = blockIdx.z;
    const int d0 = blockIdx.x * 4;
    const int h0 = blockIdx.y * 256 + tx * 4;
    const int e0 = ty * 64;
    const float* ar = attn + ((long)b * DEC + d0) * ENC + e0;
    const float* We = enc + ((long)b * ENC + e0) * HDIM + h0;

    float acc[4][4] = {};
    float4 Wa[8], Wb[8], Xa[4][2], Xb[4][2];

    CLOAD(Xa, Wa, 0)
    for (int k0 = 0; k0 < 64; k0 += 16) {
        CLOAD(Xb, Wb, k0 + 8)
        PFMA(Xa, Wa)
        if (k0 + 16 < 64) { CLOAD(Xa, Wa, k0 + 16) }
        PFMA(Xb, Wb)
    }

    if (ty > 0) {
#pragma unroll
        for (int i = 0; i < 4; ++i)
#pragma unroll
            for (int j = 0; j < 4; ++j)
                red[ty - 1][i * 4 + j][tx] = acc[i][j];
    }
    __syncthreads();
    if (ty == 0) {
#pragma unroll
        for (int i = 0; i < 4; ++i) {
#pragma unroll
            for (int j = 0; j < 4; ++j)
                acc[i][j] += red[0][i * 4 + j][tx] + red[1][i * 4 + j][tx]
                           + red[2][i * 4 + j][tx];
            *(float4*)&ctx[((long)b * DEC + d0 + i) * HDIM + h0] =
                make_float4(acc[i][0], acc[i][1], acc[i][2], acc[i][3]);
        }
    }
}

// ---------------------------------------------------------------------------
extern "C" void kernel_launch(void* const* d_in, const int* in_sizes, int n_in,
                              void* d_out, int out_size, void* d_ws, size_t ws_size,
                              hipStream_t stream) {
    const float* dec = (const float*)d_in[0];
    const float* enc = (const float*)d_in[1];
    const unsigned char* extm = (const unsigned char*)d_in[2];
    const float* Wmlp = (const float*)d_in[3];
    const float* bmlp = (const float*)d_in[4];
    const float* Wout = (const float*)d_in[5];
    // d_in[6] = b_out: additive constant, cancels in softmax

    float* ctx = (float*)d_out;                    // [B, DEC, H]
    float* attn = ctx + (size_t)B * DEC * HDIM;    // [B, DEC, ENC]

    float* ET = (float*)d_ws;                      // [B][H][ENC] exp2(scaled enc-proj)^T
    float* Dmat = ET + (size_t)B * HDIM * ENC;     // [B*DEC][H] exp2(scaled dec-proj + bias)

    proj_kernel<<<dim3(256, 1, 2), 256, 0, stream>>>(enc, dec, Wmlp, bmlp, ET, Dmat);
    attn_kernel<<<dim3(DEC / 2, B), 256, 0, stream>>>(Dmat, ET, Wout, enc, extm, attn);
    context_kernel<<<dim3(64, 2, B), 256, 0, stream>>>(attn, enc, ctx);
}

// Round 5
// 120.326 us; speedup vs baseline: 1.6526x; 1.1318x over previous
//
#include <hip/hip_runtime.h>
#include <math.h>

#define B 4
#define DEC 256
#define ENC 256
#define HDIM 512

// exp2(x*TANH_SCALE) == e^{2x};  tanh(x) = 1 - 2/(1+e^{2x})
#define TANH_SCALE 2.8853900817779268f
#define LOG2E 1.4426950408889634f

__device__ __forceinline__ float fast_exp2(float x) { return __builtin_amdgcn_exp2f(x); }
__device__ __forceinline__ float fast_rcp(float x)  { return __builtin_amdgcn_rcpf(x); }

// ---------------------------------------------------------------------------
// proj v3: 8 rows x 512 m per block, 512 threads.
//   tx = tid & 127  -> m-quad (m0 = tx*4, covers all 512 m)
//   kh = tid >> 7   -> K-quarter (128 k each), wave-uniform (readfirstlane)
// X row reads are wave-uniform -> scalar (s_load) into SGPRs: zero VGPR cost,
// zero vmcnt pressure. W reads coalesced float4, 8-deep register ping-pong.
// 4-way LDS reduce (SoA, conflict-free), exp2 epilogue on kh==0 threads.
// W L2 traffic: 128 blocks/z x 1 MB = 256 MB total (~7.4 us at L2 ceiling).
// grid (128,1,2) = 256 blocks = 1 block/CU (8 waves/CU, 2 waves/SIMD).
//  z=0: E^T[b][m][e] = exp2(TANH_SCALE * enc@W_mlp[:H])
//  z=1: D[b*DEC+d][m] = exp2(TANH_SCALE * (dec@W_mlp[H:] + b_mlp))
// ---------------------------------------------------------------------------
#define PW_LOAD(WB, KOFF)                                                   \
    _Pragma("unroll")                                                       \
    for (int kk = 0; kk < 8; ++kk)                                          \
        WB[kk] = *(const float4*)&Wp[(long)((KOFF) + kk) * 512];

#define PW_FMA(WB, KOFF)                                                    \
    _Pragma("unroll")                                                       \
    for (int kk = 0; kk < 8; ++kk) {                                        \
        float4 w = WB[kk];                                                  \
        _Pragma("unroll")                                                   \
        for (int r = 0; r < 8; ++r) {                                       \
            float xv = xr[(long)r * HDIM + (KOFF) + kk];  /* s_load */      \
            acc[r][0] = fmaf(xv, w.x, acc[r][0]);                           \
            acc[r][1] = fmaf(xv, w.y, acc[r][1]);                           \
            acc[r][2] = fmaf(xv, w.z, acc[r][2]);                           \
            acc[r][3] = fmaf(xv, w.w, acc[r][3]);                           \
        }                                                                   \
    }

__global__ __launch_bounds__(512) void proj_kernel(
    const float* __restrict__ enc, const float* __restrict__ dec,
    const float* __restrict__ Wmlp, const float* __restrict__ bmlp,
    float* __restrict__ ET, float* __restrict__ Dmat)
{
    __shared__ float red[3][32][128];   // [kh-1][acc_idx][tx] : conflict-free
    const int tid = threadIdx.x;
    const int tx = tid & 127;
    const int kh = __builtin_amdgcn_readfirstlane(tid >> 7);  // wave-uniform
    const int m0 = tx * 4;
    const int r0 = blockIdx.x * 8;
    const bool encside = (blockIdx.z == 0);
    const float* X = encside ? enc : dec;
    const float* Wp = (encside ? Wmlp : Wmlp + HDIM * HDIM)
                      + (long)kh * 128 * 512 + m0;
    const float* xr = X + (long)r0 * HDIM + kh * 128;   // uniform -> SGPR base

    float acc[8][4] = {};
    float4 Wa[8], Wb[8];

    PW_LOAD(Wa, 0)
    for (int k0 = 0; k0 < 128; k0 += 16) {
        PW_LOAD(Wb, k0 + 8)
        PW_FMA(Wa, k0)
        if (k0 + 16 < 128) { PW_LOAD(Wa, k0 + 16) }
        PW_FMA(Wb, k0 + 8)
    }

    if (kh > 0) {
#pragma unroll
        for (int r = 0; r < 8; ++r)
#pragma unroll
            for (int j = 0; j < 4; ++j)
                red[kh - 1][r * 4 + j][tx] = acc[r][j];
    }
    __syncthreads();
    if (kh == 0) {
#pragma unroll
        for (int r = 0; r < 8; ++r)
#pragma unroll
            for (int j = 0; j < 4; ++j)
                acc[r][j] += red[0][r * 4 + j][tx] + red[1][r * 4 + j][tx]
                           + red[2][r * 4 + j][tx];

        if (encside) {
            // block's 8 rows = 8 consecutive e; write E^T[b][m][e]
            const int batch = r0 >> 8, e0 = r0 & 255;
            float* outb = ET + (long)batch * HDIM * ENC + e0;
#pragma unroll
            for (int j = 0; j < 4; ++j) {
                float4 lo, hi;
                lo.x = fast_exp2(acc[0][j] * TANH_SCALE);
                lo.y = fast_exp2(acc[1][j] * TANH_SCALE);
                lo.z = fast_exp2(acc[2][j] * TANH_SCALE);
                lo.w = fast_exp2(acc[3][j] * TANH_SCALE);
                hi.x = fast_exp2(acc[4][j] * TANH_SCALE);
                hi.y = fast_exp2(acc[5][j] * TANH_SCALE);
                hi.z = fast_exp2(acc[6][j] * TANH_SCALE);
                hi.w = fast_exp2(acc[7][j] * TANH_SCALE);
                *(float4*)&outb[(long)(m0 + j) * ENC] = lo;
                *(float4*)&outb[(long)(m0 + j) * ENC + 4] = hi;
            }
        } else {
            const float4 bq = *(const float4*)&bmlp[m0];
            float* outb = Dmat + (long)r0 * HDIM + m0;
#pragma unroll
            for (int r = 0; r < 8; ++r) {
                float4 v;
                v.x = fast_exp2((acc[r][0] + bq.x) * TANH_SCALE);
                v.y = fast_exp2((acc[r][1] + bq.y) * TANH_SCALE);
                v.z = fast_exp2((acc[r][2] + bq.z) * TANH_SCALE);
                v.w = fast_exp2((acc[r][3] + bq.w) * TANH_SCALE);
                *(float4*)&outb[(long)r * HDIM] = v;
            }
        }
    }
}

// ---------------------------------------------------------------------------
// attn: thread = e (256/block), 2 decoder rows/block, 512 blocks (2/CU).
// acc_d = sum_m wo[m] * rcp(fma(E[e,m], D[d,m], 1)); logit = -2*acc (constants
// cancel in softmax). 3 VALU insts/element. 16-deep register prefetch on E^T.
// ---------------------------------------------------------------------------
__global__ __launch_bounds__(256) void attn_kernel(
    const float* __restrict__ Dmat, const float* __restrict__ ET,
    const float* __restrict__ wo,
    const float* __restrict__ enc, const unsigned char* __restrict__ extm,
    float* __restrict__ attn_out)
{
    __shared__ float red[2][4][2];
    const int tid = threadIdx.x, lane = tid & 63, wave = tid >> 6;
    const int b = blockIdx.y, d0 = blockIdx.x * 2;

    const float* D0 = Dmat + ((long)b * DEC + d0) * HDIM;
    const float* D1 = D0 + HDIM;
    const float* ecol = ET + (long)b * HDIM * ENC + tid;

    float acc0 = 0.f, acc1 = 0.f;
    float ev[16], nv[16];
#pragma unroll
    for (int j = 0; j < 16; ++j) ev[j] = ecol[j * ENC];

    for (int m = 0; m < HDIM; m += 16) {
        if (m + 16 < HDIM) {
#pragma unroll
            for (int j = 0; j < 16; ++j) nv[j] = ecol[(m + 16 + j) * ENC];
        }
#pragma unroll
        for (int j = 0; j < 16; ++j) {
            float w = wo[m + j];                        // uniform -> s_load
            float t0 = fmaf(ev[j], D0[m + j], 1.0f);
            float t1 = fmaf(ev[j], D1[m + j], 1.0f);
            acc0 = fmaf(w, fast_rcp(t0), acc0);
            acc1 = fmaf(w, fast_rcp(t1), acc1);
        }
#pragma unroll
        for (int j = 0; j < 16; ++j) ev[j] = nv[j];
    }

    // masks + effective logits
    const int e = tid;
    const bool pad = (enc[((long)b * ENC + e) * HDIM] == 0.0f);
    const bool x0m = extm[((long)(b * DEC) + d0) * ENC + e] != 0;
    const bool x1m = extm[((long)(b * DEC) + d0 + 1) * ENC + e] != 0;
    float l0 = (pad || x0m) ? -__builtin_inff() : -2.0f * acc0;
    float l1 = (pad || x1m) ? -__builtin_inff() : -2.0f * acc1;

    // softmax over e (4 waves)
    float m0 = l0, m1 = l1;
#pragma unroll
    for (int off = 32; off >= 1; off >>= 1) {
        m0 = fmaxf(m0, __shfl_xor(m0, off, 64));
        m1 = fmaxf(m1, __shfl_xor(m1, off, 64));
    }
    if (lane == 0) { red[0][wave][0] = m0; red[0][wave][1] = m1; }
    __syncthreads();
    const float gm0 = fmaxf(fmaxf(red[0][0][0], red[0][1][0]), fmaxf(red[0][2][0], red[0][3][0]));
    const float gm1 = fmaxf(fmaxf(red[0][0][1], red[0][1][1]), fmaxf(red[0][2][1], red[0][3][1]));
    float p0 = fast_exp2((l0 - gm0) * LOG2E);
    float p1 = fast_exp2((l1 - gm1) * LOG2E);
    float s0 = p0, s1 = p1;
#pragma unroll
    for (int off = 32; off >= 1; off >>= 1) {
        s0 += __shfl_xor(s0, off, 64);
        s1 += __shfl_xor(s1, off, 64);
    }
    if (lane == 0) { red[1][wave][0] = s0; red[1][wave][1] = s1; }
    __syncthreads();
    const float gs0 = red[1][0][0] + red[1][1][0] + red[1][2][0] + red[1][3][0];
    const float gs1 = red[1][0][1] + red[1][1][1] + red[1][2][1] + red[1][3][1];
    attn_out[((long)(b * DEC) + d0) * ENC + e] = p0 * fast_rcp(gs0);
    attn_out[((long)(b * DEC) + d0 + 1) * ENC + e] = p1 * fast_rcp(gs1);
}

// ---------------------------------------------------------------------------
// context: 4 d x 256 h per block, 256 thr. tx = tid&63 -> h-quad, ty = tid>>6
// -> e-quarter (64 e each). Each thread: 4d x 4h x 64e; LDS 4-way reduce.
// grid (64, 2, B) = 512 blocks -> 2 blocks/CU.
// ---------------------------------------------------------------------------
#define CFMA(XB, WB)                                                        \
    _Pragma("unroll")                                                       \
    for (int kk = 0; kk < 8; ++kk) {                                        \
        _Pragma("unroll")                                                   \
        for (int i = 0; i < 4; ++i) {                                       \
            float xv = ((const float*)&XB[i][kk >> 2])[kk & 3];             \
            acc[i][0] = fmaf(xv, WB[kk].x, acc[i][0]);                      \
            acc[i][1] = fmaf(xv, WB[kk].y, acc[i][1]);                      \
            acc[i][2] = fmaf(xv, WB[kk].z, acc[i][2]);                      \
            acc[i][3] = fmaf(xv, WB[kk].w, acc[i][3]);                      \
        }                                                                   \
    }

#define CLOAD(XB, WB, KOFF)                                                 \
    _Pragma("unroll")                                                       \
    for (int kk = 0; kk < 8; ++kk)                                          \
        WB[kk] = *(const float4*)&We[(long)((KOFF) + kk) * HDIM];           \
    _Pragma("unroll")                                                       \
    for (int i = 0; i < 4; ++i) {                                           \
        XB[i][0] = *(const float4*)&ar[(long)i * ENC + (KOFF)];             \
        XB[i][1] = *(const float4*)&ar[(long)i * ENC + (KOFF) + 4];         \
    }

__global__ __launch_bounds__(256) void context_kernel(
    const float* __restrict__ attn, const float* __restrict__ enc,
    float* __restrict__ ctx)
{
    __shared__ float red[3][16][64];
    const int tid = threadIdx.x;
    const int tx = tid & 63, ty = tid >> 6;
    const int b = blockIdx.z;
    const int d0 = blockIdx.x * 4;
    const int h0 = blockIdx.y * 256 + tx * 4;
    const int e0 = ty * 64;
    const float* ar = attn + ((long)b * DEC + d0) * ENC + e0;
    const float* We = enc + ((long)b * ENC + e0) * HDIM + h0;

    float acc[4][4] = {};
    float4 Wa[8], Wb[8], Xa[4][2], Xb[4][2];

    CLOAD(Xa, Wa, 0)
    for (int k0 = 0; k0 < 64; k0 += 16) {
        CLOAD(Xb, Wb, k0 + 8)
        CFMA(Xa, Wa)
        if (k0 + 16 < 64) { CLOAD(Xa, Wa, k0 + 16) }
        CFMA(Xb, Wb)
    }

    if (ty > 0) {
#pragma unroll
        for (int i = 0; i < 4; ++i)
#pragma unroll
            for (int j = 0; j < 4; ++j)
                red[ty - 1][i * 4 + j][tx] = acc[i][j];
    }
    __syncthreads();
    if (ty == 0) {
#pragma unroll
        for (int i = 0; i < 4; ++i) {
#pragma unroll
            for (int j = 0; j < 4; ++j)
                acc[i][j] += red[0][i * 4 + j][tx] + red[1][i * 4 + j][tx]
                           + red[2][i * 4 + j][tx];
            *(float4*)&ctx[((long)b * DEC + d0 + i) * HDIM + h0] =
                make_float4(acc[i][0], acc[i][1], acc[i][2], acc[i][3]);
        }
    }
}

// ---------------------------------------------------------------------------
extern "C" void kernel_launch(void* const* d_in, const int* in_sizes, int n_in,
                              void* d_out, int out_size, void* d_ws, size_t ws_size,
                              hipStream_t stream) {
    const float* dec = (const float*)d_in[0];
    const float* enc = (const float*)d_in[1];
    const unsigned char* extm = (const unsigned char*)d_in[2];
    const float* Wmlp = (const float*)d_in[3];
    const float* bmlp = (const float*)d_in[4];
    const float* Wout = (const float*)d_in[5];
    // d_in[6] = b_out: additive constant, cancels in softmax

    float* ctx = (float*)d_out;                    // [B, DEC, H]
    float* attn = ctx + (size_t)B * DEC * HDIM;    // [B, DEC, ENC]

    float* ET = (float*)d_ws;                      // [B][H][ENC] exp2(scaled enc-proj)^T
    float* Dmat = ET + (size_t)B * HDIM * ENC;     // [B*DEC][H] exp2(scaled dec-proj + bias)

    proj_kernel<<<dim3(128, 1, 2), 512, 0, stream>>>(enc, dec, Wmlp, bmlp, ET, Dmat);
    attn_kernel<<<dim3(DEC / 2, B), 256, 0, stream>>>(Dmat, ET, Wout, enc, extm, attn);
    context_kernel<<<dim3(64, 2, B), 256, 0, stream>>>(attn, enc, ctx);
}